// Round 11
// baseline (145.808 us; speedup 1.0000x reference)
//
#include <hip/hip_runtime.h>

#define NB 32
#define WPB 4   // 4 tokens (waves) per 256-thread block

__device__ __forceinline__ float clamp01(float x) {
    return fminf(fmaxf(x, 0.0f), 1.0f);
}

// ============================ kernel 1: h_new ============================
// One wave per token. Lane (i = lw&31, half = lw>>5) owns the row-slice
// W[i][half*16 .. half*16+15] in registers (4 strided float4 loads; each
// 128B row-line fully covered by its 2 owning lanes). Inflow partials over
// the 16 owned columns merge across halves with one __shfl_xor(32) set.
// LDS = h broadcast only (512B/wave, wave-private -> no __syncthreads).
__global__ __launch_bounds__(256, 8) void biotoken_hnew(
    const float* __restrict__ h,
    const float* __restrict__ W,
    const float* __restrict__ stim,
    float* __restrict__ out_h)
{
    const int lw    = threadIdx.x & 63;
    const int wave  = threadIdx.x >> 6;
    const int token = blockIdx.x * WPB + wave;
    const int i     = lw & 31;            // row this lane owns
    const int half  = lw >> 5;
    const int c0    = half * 16;          // first owned column

    __shared__ float s_hin[WPB][NB * 4];

    const float*  Wt  = W + (size_t)token * (NB * NB);
    const float4* wrp = (const float4*)(Wt + i * NB + c0);
    float4 wrow[4];
    wrow[0] = wrp[0]; wrow[1] = wrp[1]; wrow[2] = wrp[2]; wrow[3] = wrp[3];

    if (lw < NB) {
        ((float4*)s_hin[wave])[lw] =
            ((const float4*)(h + (size_t)token * (NB * 4)))[lw];
    }
    const float sti = stim[(size_t)token * NB + i];   // 128B broadcast
    __builtin_amdgcn_wave_barrier();      // scheduling fence (wave-private LDS)

    const float* shin = s_hin[wave];
    const float* wf   = (const float*)wrow;   // static indices after unroll

    float accE = 0.f, accP = 0.f, accG = 0.f, accL = 0.f, tot = 0.f;
    #pragma unroll
    for (int t = 0; t < 16; ++t) {
        const int j = c0 + t;
        float w = wf[t];
        w = (j == i) ? 0.0f : w;                 // zero self-connection
        const float4 hj = *(const float4*)&shin[j * 4];   // broadcast read
        accE = fmaf(w, hj.x, accE);
        accP = fmaf(w, hj.y, accP);
        accG = fmaf(w, hj.z, accG);
        accL = fmaf(w, hj.w, accL);
        tot += w;
    }
    accE += __shfl_xor(accE, 32);
    accP += __shfl_xor(accP, 32);
    accG += __shfl_xor(accG, 32);
    accL += __shfl_xor(accL, 32);
    tot  += __shfl_xor(tot,  32);

    const float inv = 1.0f / (tot + 1e-8f);
    const float En = accE * inv, Pn = accP * inv, Gn = accG * inv, Ln = accL * inv;

    const float4 hi = *(const float4*)&shin[i * 4];
    const float E = hi.x, P = hi.y, G = hi.z, L = hi.w;

    const float E_new = clamp01(E + 0.3f * sti - 0.4f * P - 0.2f * G);
    const float P_new = clamp01(P + 0.5f * sti + 0.3f * (Pn - P) - 0.2f * E);
    const float G_new = clamp01(G + 0.4f * E * (1.0f - P) + 0.2f * (Gn - G) - 0.3f * P);
    const float good  = 0.5f * En + 0.5f * Gn;
    const float L_new = clamp01(L + 0.4f * good + 0.3f * (Ln - L) - 0.3f * P);

    if (half == 0) {
        ((float4*)(out_h + (size_t)token * (NB * 4)))[i] =
            make_float4(E_new, P_new, G_new, L_new);
    }
}

// ============================ kernel 2: W_new ============================
// Pure stream: one wave per token. W loaded m-layout (coalesced 1KB/instr)
// straight into registers; h_new (written by kernel 1) broadcast via 512B
// wave-private LDS; 16 distance/updates per lane; coalesced m-layout store.
// No barriers, no W LDS copy, short dependency chains.
__global__ __launch_bounds__(256, 6) void biotoken_wnew(
    const float* __restrict__ W,
    const float* __restrict__ hn,
    float* __restrict__ out_W)
{
    const int lw    = threadIdx.x & 63;
    const int wave  = threadIdx.x >> 6;
    const int token = blockIdx.x * WPB + wave;

    __shared__ float s_hn[WPB][NB * 4];

    const float4* Wt = (const float4*)(W + (size_t)token * (NB * NB));
    // all 4 W loads issued up front (no barrier between issue and use)
    float4 wrs[4];
    wrs[0] = Wt[0 * 64 + lw];
    wrs[1] = Wt[1 * 64 + lw];
    wrs[2] = Wt[2 * 64 + lw];
    wrs[3] = Wt[3 * 64 + lw];

    if (lw < NB) {
        ((float4*)s_hn[wave])[lw] =
            ((const float4*)(hn + (size_t)token * (NB * 4)))[lw];
    }
    __builtin_amdgcn_wave_barrier();      // scheduling fence (wave-private LDS)

    const float* shn = s_hn[wave];
    // hj columns depend only on lw&7, not k (m = k*64+lw, 64 % 8 == 0)
    const int jb0 = (lw & 7) * 4;
    float4 hjv[4];
    #pragma unroll
    for (int e = 0; e < 4; ++e) {
        hjv[e] = *(const float4*)&shn[(jb0 + e) * 4];
    }

    float4* outWt = (float4*)(out_W + (size_t)token * (NB * NB));
    #pragma unroll
    for (int k = 0; k < 4; ++k) {
        const int m = k * 64 + lw;        // float4 index in token's W
        const int r = m >> 3;             // row
        const float4 hr = *(const float4*)&shn[r * 4];
        const float  Lr = hr.w;
        const float* wp = (const float*)&wrs[k];
        float4 res;
        float* resp = &res.x;
        #pragma unroll
        for (int e = 0; e < 4; ++e) {
            const int j = jb0 + e;
            const float4 hj = hjv[e];
            const float dx = hr.x - hj.x;
            const float dy = hr.y - hj.y;
            const float dz = hr.z - hj.z;
            const float dw = hr.w - hj.w;
            const float sq = dx * dx + dy * dy + dz * dz + dw * dw;
            const float dist = sqrtf(sq);               // sqrt(0)=0 matches ref
            const float mutual = 0.5f * (Lr + hj.w);
            float wn = 0.95f * wp[e] + 0.1f * mutual * dist;
            wn = clamp01(wn);
            resp[e] = (j == r) ? 0.0f : wn;             // zero diagonal
        }
        outWt[m] = res;                   // coalesced 1KB/instr store
    }
}

extern "C" void kernel_launch(void* const* d_in, const int* in_sizes, int n_in,
                              void* d_out, int out_size, void* d_ws, size_t ws_size,
                              hipStream_t stream) {
    const float* h    = (const float*)d_in[0];  // [8,2048,32,4]
    const float* W    = (const float*)d_in[1];  // [8,2048,32,32]
    const float* stim = (const float*)d_in[2];  // [8,2048,32]

    const int tokens = in_sizes[2] / NB;        // 16384
    float* out_h = (float*)d_out;               // [8,2048,32,4]
    float* out_W = (float*)d_out + (size_t)tokens * NB * 4;  // [8,2048,32,32]

    const int blocks = tokens / WPB;            // 4096
    // k2 depends on k1's out_h; same-stream ordering guarantees visibility.
    biotoken_hnew<<<blocks, 256, 0, stream>>>(h, W, stim, out_h);
    biotoken_wnew<<<blocks, 256, 0, stream>>>(W, out_h, out_W);
}